// Round 1
// baseline (239.179 us; speedup 1.0000x reference)
//
#include <hip/hip_runtime.h>
#include <math.h>

#define N     12
#define HID   64
#define ST    68        // padded LDS row stride (16B-aligned rows, kills bank conflicts)
#define SLOPE 0.2f
#define ALPHA 0.1f

// flat output offsets (float32 elements)
#define OUT0 0          // batch[:,:,:4]  (4096*12*4)
#define OUT1 196608     // batch[:,:,4:5] (4096*12)
#define OUT2 245760     // logits         (4096*12*4)
#define OUT3 442368     // values         (4096*12)
#define OUT4 491520     // latent         (4096*12*3)

__global__ __launch_bounds__(64, 2) void gae_kernel(
    const float* __restrict__ batch,
    const float* __restrict__ enc_w1, const float* __restrict__ enc_b1,
    const float* __restrict__ enc_w2, const float* __restrict__ enc_b2,
    const float* __restrict__ enc_w3, const float* __restrict__ enc_b3,
    const float* __restrict__ g1_wl, const float* __restrict__ g1_wr,
    const float* __restrict__ g1_att, const float* __restrict__ g1_b,
    const float* __restrict__ g2_wl, const float* __restrict__ g2_wr,
    const float* __restrict__ g2_att, const float* __restrict__ g2_b,
    const float* __restrict__ g3_wl, const float* __restrict__ g3_wr,
    const float* __restrict__ g3_att, const float* __restrict__ g3_b,
    const float* __restrict__ g4_wl, const float* __restrict__ g4_wr,
    const float* __restrict__ g4_att, const float* __restrict__ g4_b,
    const float* __restrict__ lab_w, const float* __restrict__ lab_b,
    const float* __restrict__ val_w, const float* __restrict__ val_b,
    const float* __restrict__ skip_w, const float* __restrict__ skip_b,
    float* __restrict__ out)
{
    const int b = blockIdx.x;
    const int t = threadIdx.x;   // 0..63, lane == hidden channel

    __shared__ __align__(16) float bufL[N*ST];   // h1, then xl per GAT layer
    __shared__ __align__(16) float bufR[N*ST];   // h2, then xr per GAT layer
    __shared__ __align__(16) float xA[N*ST];     // x1 / x3 / x4
    __shared__ __align__(16) float xB[N*ST];     // x2 (persists for g3 & g4)
    __shared__ __align__(16) float skip_s[N*ST];
    __shared__ __align__(16) float att_s[HID];
    __shared__ float batch_s[N*5];
    __shared__ float lat_s[N*3];
    __shared__ float x0_s[N];
    __shared__ float e_s[N*N];                   // scores, then softmax weights (in place)
    __shared__ int   gab_s[N*N];

    // ---- stage batch, emit passthrough outputs 0 and 1 ----
    if (t < N*5) {
        float v = batch[b*(N*5) + t];
        batch_s[t] = v;
        int i = t / 5, f = t - i*5;
        if (f < 4) out[OUT0 + (size_t)b*(N*4) + i*4 + f] = v;
        else       out[OUT1 + (size_t)b*N + i] = v;
    }
    __syncthreads();

    // ---- encoder layer 1: h1 = relu(batch @ W1 + b1) ----
    {
        float acc[N];
        float bias = enc_b1[t];
        #pragma unroll
        for (int i=0;i<N;i++) acc[i] = bias;
        #pragma unroll
        for (int f=0; f<5; f++) {
            float w = enc_w1[f*HID + t];
            #pragma unroll
            for (int i=0;i<N;i++) acc[i] = fmaf(batch_s[i*5+f], w, acc[i]);
        }
        #pragma unroll
        for (int i=0;i<N;i++) bufL[i*ST+t] = fmaxf(acc[i], 0.f);
    }
    __syncthreads();

    // ---- encoder layer 2: h2 = relu(h1 @ W2 + b2) ----
    {
        float acc[N];
        float bias = enc_b2[t];
        #pragma unroll
        for (int i=0;i<N;i++) acc[i] = bias;
        for (int c=0;c<HID;c+=4) {
            float w0 = enc_w2[(c+0)*HID+t];
            float w1 = enc_w2[(c+1)*HID+t];
            float w2 = enc_w2[(c+2)*HID+t];
            float w3 = enc_w2[(c+3)*HID+t];
            #pragma unroll
            for (int i=0;i<N;i++) {
                float4 xv = *reinterpret_cast<const float4*>(&bufL[i*ST+c]);
                acc[i] = fmaf(xv.x, w0, acc[i]);
                acc[i] = fmaf(xv.y, w1, acc[i]);
                acc[i] = fmaf(xv.z, w2, acc[i]);
                acc[i] = fmaf(xv.w, w3, acc[i]);
            }
        }
        #pragma unroll
        for (int i=0;i<N;i++) bufR[i*ST+t] = fmaxf(acc[i], 0.f);
    }
    __syncthreads();

    // ---- latent = h2 @ W3 + b3 (36 outputs; lanes 0..35) ----
    if (t < N*3) {
        int i = t / 3, c = t - i*3;
        float acc = enc_b3[c];
        for (int k=0;k<HID;k+=4) {
            float4 xv = *reinterpret_cast<const float4*>(&bufR[i*ST+k]);
            acc = fmaf(xv.x, enc_w3[(k+0)*3+c], acc);
            acc = fmaf(xv.y, enc_w3[(k+1)*3+c], acc);
            acc = fmaf(xv.z, enc_w3[(k+2)*3+c], acc);
            acc = fmaf(xv.w, enc_w3[(k+3)*3+c], acc);
        }
        lat_s[t] = acc;
        out[OUT4 + (size_t)b*(N*3) + t] = acc;
        if (c == 2) x0_s[i] = acc;
    }
    __syncthreads();

    // ---- skip = latent @ skip_w + skip_b (lane = channel t) ----
    {
        float w0 = skip_w[t], w1 = skip_w[HID+t], w2 = skip_w[2*HID+t];
        float bias = skip_b[t];
        #pragma unroll
        for (int i=0;i<N;i++) {
            float v = bias;
            v = fmaf(lat_s[i*3+0], w0, v);
            v = fmaf(lat_s[i*3+1], w1, v);
            v = fmaf(lat_s[i*3+2], w2, v);
            skip_s[i*ST+t] = v;
        }
    }

    // ---- Gabriel adjacency candidate matrix gab_s ----
    for (int p = t; p < N*N; p += 64) {
        int i = p / N, j = p - i*N;
        int g = 0;
        if (i != j) {
            float pix = lat_s[i*3], piy = lat_s[i*3+1];
            float pjx = lat_s[j*3], pjy = lat_s[j*3+1];
            float mx = (pix + pjx) * 0.5f, my = (piy + pjy) * 0.5f;
            float dx = pix - pjx, dy = piy - pjy;
            float r2 = (dx*dx + dy*dy) * 0.25f;
            g = 1;
            #pragma unroll
            for (int k=0;k<N;k++) {
                if (k == i || k == j) continue;
                float ex = lat_s[k*3] - mx, ey = lat_s[k*3+1] - my;
                float d2 = ex*ex + ey*ey;
                g &= (d2 > r2) ? 1 : 0;
            }
        }
        gab_s[p] = g;
    }
    __syncthreads();

    // ---- GATv2 core: scores -> masked softmax -> aggregate (+optional skip) ----
    auto gat_core = [&](const float* __restrict__ gb, float* __restrict__ xout,
                        const float* __restrict__ skipb) {
        __syncthreads();   // xl/xr/att_s staged by caller
        for (int p = t; p < N*N; p += 64) {
            int i = p / N, j = p - i*N;
            float acc = 0.f;
            for (int h=0; h<HID; h+=4) {
                float4 xl4 = *reinterpret_cast<const float4*>(&bufL[j*ST+h]);
                float4 xr4 = *reinterpret_cast<const float4*>(&bufR[i*ST+h]);
                float4 a4  = *reinterpret_cast<const float4*>(&att_s[h]);
                float s;
                s = xl4.x + xr4.x; s = s > 0.f ? s : SLOPE*s; acc = fmaf(a4.x, s, acc);
                s = xl4.y + xr4.y; s = s > 0.f ? s : SLOPE*s; acc = fmaf(a4.y, s, acc);
                s = xl4.z + xr4.z; s = s > 0.f ? s : SLOPE*s; acc = fmaf(a4.z, s, acc);
                s = xl4.w + xr4.w; s = s > 0.f ? s : SLOPE*s; acc = fmaf(a4.w, s, acc);
            }
            int adj = gab_s[i*N+j] | gab_s[j*N+i] | ((i == j) ? 1 : 0);
            e_s[p] = adj ? acc : -1e9f;
        }
        __syncthreads();
        if (t < N) {   // row-wise softmax, lane = row
            float m = -2e9f;
            #pragma unroll
            for (int j=0;j<N;j++) m = fmaxf(m, e_s[t*N+j]);
            float tmp[N]; float sum = 0.f;
            #pragma unroll
            for (int j=0;j<N;j++) { float v = expf(e_s[t*N+j] - m); tmp[j] = v; sum += v; }
            float inv = 1.0f / sum;
            #pragma unroll
            for (int j=0;j<N;j++) e_s[t*N+j] = tmp[j] * inv;
        }
        __syncthreads();
        {
            float bias = gb[t];
            #pragma unroll
            for (int i=0;i<N;i++) {
                float acc = bias;
                #pragma unroll
                for (int j=0;j<N;j++) acc = fmaf(e_s[i*N+j], bufL[j*ST+t], acc);
                if (skipb) acc = fmaf(ALPHA, skipb[i*ST+t], acc);
                xout[i*ST+t] = fmaxf(acc, 0.f);
            }
        }
        __syncthreads();
    };

    // ---- stage xl/xr for a 64-channel input layer ----
    auto stage_lr = [&](const float* __restrict__ xin, const float* __restrict__ wl,
                        const float* __restrict__ wr, const float* __restrict__ att) {
        att_s[t] = att[t];
        float xl[N], xr[N];
        #pragma unroll
        for (int i=0;i<N;i++) { xl[i] = 0.f; xr[i] = 0.f; }
        for (int c=0;c<HID;c+=4) {
            float wl0 = wl[(c+0)*HID+t], wr0 = wr[(c+0)*HID+t];
            float wl1 = wl[(c+1)*HID+t], wr1 = wr[(c+1)*HID+t];
            float wl2 = wl[(c+2)*HID+t], wr2 = wr[(c+2)*HID+t];
            float wl3 = wl[(c+3)*HID+t], wr3 = wr[(c+3)*HID+t];
            #pragma unroll
            for (int i=0;i<N;i++) {
                float4 xv = *reinterpret_cast<const float4*>(&xin[i*ST+c]);
                xl[i] = fmaf(xv.x, wl0, xl[i]); xr[i] = fmaf(xv.x, wr0, xr[i]);
                xl[i] = fmaf(xv.y, wl1, xl[i]); xr[i] = fmaf(xv.y, wr1, xr[i]);
                xl[i] = fmaf(xv.z, wl2, xl[i]); xr[i] = fmaf(xv.z, wr2, xr[i]);
                xl[i] = fmaf(xv.w, wl3, xl[i]); xr[i] = fmaf(xv.w, wr3, xr[i]);
            }
        }
        #pragma unroll
        for (int i=0;i<N;i++) { bufL[i*ST+t] = xl[i]; bufR[i*ST+t] = xr[i]; }
    };

    // ---- GAT layer 1 (cin = 1, x0 = latent[...,2]) ----
    {
        att_s[t] = g1_att[t];
        float wlv = g1_wl[t], wrv = g1_wr[t];
        #pragma unroll
        for (int i=0;i<N;i++) {
            bufL[i*ST+t] = x0_s[i] * wlv;
            bufR[i*ST+t] = x0_s[i] * wrv;
        }
    }
    gat_core(g1_b, xA, nullptr);          // x1 -> xA

    // ---- GAT layer 2 ----
    stage_lr(xA, g2_wl, g2_wr, g2_att);
    gat_core(g2_b, xB, nullptr);          // x2 -> xB (persists)

    // ---- GAT layer 3 (+ ALPHA*skip) ----
    stage_lr(xB, g3_wl, g3_wr, g3_att);
    gat_core(g3_b, xA, skip_s);           // x3 -> xA

    // ---- logits head: x3 @ lab_w + lab_b ----
    if (t < N*4) {
        int i = t >> 2, c = t & 3;
        float acc = lab_b[c];
        for (int h=0;h<HID;h+=4) {
            float4 xv = *reinterpret_cast<const float4*>(&xA[i*ST+h]);
            acc = fmaf(xv.x, lab_w[(h+0)*4+c], acc);
            acc = fmaf(xv.y, lab_w[(h+1)*4+c], acc);
            acc = fmaf(xv.z, lab_w[(h+2)*4+c], acc);
            acc = fmaf(xv.w, lab_w[(h+3)*4+c], acc);
        }
        out[OUT2 + (size_t)b*(N*4) + t] = acc;
    }

    // ---- GAT layer 4 (+ ALPHA*skip) ----
    stage_lr(xB, g4_wl, g4_wr, g4_att);
    gat_core(g4_b, xA, skip_s);           // x4 -> xA

    // ---- values head: x4 @ val_w + val_b ----
    if (t < N) {
        float acc = val_b[0];
        for (int h=0;h<HID;h+=4) {
            float4 xv = *reinterpret_cast<const float4*>(&xA[t*ST+h]);
            acc = fmaf(xv.x, val_w[h+0], acc);
            acc = fmaf(xv.y, val_w[h+1], acc);
            acc = fmaf(xv.z, val_w[h+2], acc);
            acc = fmaf(xv.w, val_w[h+3], acc);
        }
        out[OUT3 + (size_t)b*N + t] = acc;
    }
}

extern "C" void kernel_launch(void* const* d_in, const int* in_sizes, int n_in,
                              void* d_out, int out_size, void* d_ws, size_t ws_size,
                              hipStream_t stream) {
    (void)in_sizes; (void)n_in; (void)d_ws; (void)ws_size; (void)out_size;
    gae_kernel<<<dim3(4096), dim3(64), 0, stream>>>(
        (const float*)d_in[0],
        (const float*)d_in[1],  (const float*)d_in[2],
        (const float*)d_in[3],  (const float*)d_in[4],
        (const float*)d_in[5],  (const float*)d_in[6],
        (const float*)d_in[7],  (const float*)d_in[8],  (const float*)d_in[9],  (const float*)d_in[10],
        (const float*)d_in[11], (const float*)d_in[12], (const float*)d_in[13], (const float*)d_in[14],
        (const float*)d_in[15], (const float*)d_in[16], (const float*)d_in[17], (const float*)d_in[18],
        (const float*)d_in[19], (const float*)d_in[20], (const float*)d_in[21], (const float*)d_in[22],
        (const float*)d_in[23], (const float*)d_in[24],
        (const float*)d_in[25], (const float*)d_in[26],
        (const float*)d_in[27], (const float*)d_in[28],
        (float*)d_out);
}

// Round 2
// 228.318 us; speedup vs baseline: 1.0476x; 1.0476x over previous
//
#include <hip/hip_runtime.h>
#include <math.h>

#define N     12
#define HID   64
#define ST    68        // padded LDS row stride (16B-aligned rows; 17 float4-banks -> conflict-free row spread)
#define SLOPE 0.2f
#define ALPHA 0.1f

typedef float v2f __attribute__((ext_vector_type(2)));
typedef float v4f __attribute__((ext_vector_type(4)));

// flat output offsets (float32 elements)
#define OUT0 0          // batch[:,:,:4]
#define OUT1 196608     // batch[:,:,4:5]
#define OUT2 245760     // logits
#define OUT3 442368     // values
#define OUT4 491520     // latent

// transpose 7 64x64 weight matrices into ws: ws[m*4096 + t*64 + c] = W[c*64 + t]
__global__ void prep_kernel(const float* __restrict__ enc_w2,
                            const float* __restrict__ g2_wl, const float* __restrict__ g2_wr,
                            const float* __restrict__ g3_wl, const float* __restrict__ g3_wr,
                            const float* __restrict__ g4_wl, const float* __restrict__ g4_wr,
                            float* __restrict__ ws) {
    int m = blockIdx.x >> 6, c = blockIdx.x & 63, t = threadIdx.x;
    const float* src;
    switch (m) {
        case 0: src = enc_w2; break;
        case 1: src = g2_wl;  break;
        case 2: src = g2_wr;  break;
        case 3: src = g3_wl;  break;
        case 4: src = g3_wr;  break;
        case 5: src = g4_wl;  break;
        default: src = g4_wr; break;
    }
    ws[m*4096 + t*64 + c] = src[c*64 + t];
}

template<bool TW>
__global__ __launch_bounds__(64, 3) void gae_kernel(
    const float* __restrict__ batch,
    const float* __restrict__ enc_w1, const float* __restrict__ enc_b1,
    const float* __restrict__ enc_w2, const float* __restrict__ enc_b2,
    const float* __restrict__ enc_w3, const float* __restrict__ enc_b3,
    const float* __restrict__ g1_wl, const float* __restrict__ g1_wr,
    const float* __restrict__ g1_att, const float* __restrict__ g1_b,
    const float* __restrict__ g2_wl, const float* __restrict__ g2_wr,
    const float* __restrict__ g2_att, const float* __restrict__ g2_b,
    const float* __restrict__ g3_wl, const float* __restrict__ g3_wr,
    const float* __restrict__ g3_att, const float* __restrict__ g3_b,
    const float* __restrict__ g4_wl, const float* __restrict__ g4_wr,
    const float* __restrict__ g4_att, const float* __restrict__ g4_b,
    const float* __restrict__ lab_w, const float* __restrict__ lab_b,
    const float* __restrict__ val_w, const float* __restrict__ val_b,
    const float* __restrict__ skip_w, const float* __restrict__ skip_b,
    const float* __restrict__ wsT,
    float* __restrict__ out)
{
    const int b = blockIdx.x;
    const int t = threadIdx.x;   // lane == hidden channel

    __shared__ __align__(16) float bufL[N*ST];
    __shared__ __align__(16) float bufR[N*ST];
    __shared__ __align__(16) float xA[N*ST];
    __shared__ __align__(16) float xB[N*ST];
    __shared__ __align__(16) float att_s[HID];
    __shared__ float batch_s[N*5];
    __shared__ float lat_s[N*3];
    __shared__ float x0_s[N];
    __shared__ float e_s[N*N];
    __shared__ unsigned char gab8[N*N];
    __shared__ unsigned adjm_s[N];

    const v2f z2 = {0.f, 0.f};
    const v2f slope2 = {SLOPE, SLOPE};

    // per-lane transposed weight rows (valid only if TW)
    const float* w2T   = TW ? (wsT + 0*4096 + t*64) : nullptr;
    const float* g2wlT = TW ? (wsT + 1*4096 + t*64) : nullptr;
    const float* g2wrT = TW ? (wsT + 2*4096 + t*64) : nullptr;
    const float* g3wlT = TW ? (wsT + 3*4096 + t*64) : nullptr;
    const float* g3wrT = TW ? (wsT + 4*4096 + t*64) : nullptr;
    const float* g4wlT = TW ? (wsT + 5*4096 + t*64) : nullptr;
    const float* g4wrT = TW ? (wsT + 6*4096 + t*64) : nullptr;

    // ---- stage batch, emit passthrough outputs 0 and 1 ----
    if (t < N*5) {
        float v = batch[b*(N*5) + t];
        batch_s[t] = v;
        int i = t / 5, f = t - i*5;
        if (f < 4) out[OUT0 + (size_t)b*(N*4) + i*4 + f] = v;
        else       out[OUT1 + (size_t)b*N + i] = v;
    }
    __syncthreads();

    // ---- encoder layer 1 ----
    {
        float acc[N];
        float bias = enc_b1[t];
        #pragma unroll
        for (int i=0;i<N;i++) acc[i] = bias;
        #pragma unroll
        for (int f=0; f<5; f++) {
            float w = enc_w1[f*HID + t];
            #pragma unroll
            for (int i=0;i<N;i++) acc[i] = fmaf(batch_s[i*5+f], w, acc[i]);
        }
        #pragma unroll
        for (int i=0;i<N;i++) bufL[i*ST+t] = fmaxf(acc[i], 0.f);
    }
    __syncthreads();

    // ---- encoder layer 2 (packed fp32) ----
    {
        v2f acc[N];
        #pragma unroll
        for (int i=0;i<N;i++) acc[i] = z2;
        for (int c=0;c<HID;c+=4) {
            v2f w01, w23;
            if (TW) {
                v4f w4 = *reinterpret_cast<const v4f*>(&w2T[c]);
                w01 = w4.xy; w23 = w4.zw;
            } else {
                w01 = (v2f){enc_w2[(c+0)*HID+t], enc_w2[(c+1)*HID+t]};
                w23 = (v2f){enc_w2[(c+2)*HID+t], enc_w2[(c+3)*HID+t]};
            }
            #pragma unroll
            for (int i=0;i<N;i++) {
                v4f xv = *reinterpret_cast<const v4f*>(&bufL[i*ST+c]);
                acc[i] = __builtin_elementwise_fma(xv.xy, w01, acc[i]);
                acc[i] = __builtin_elementwise_fma(xv.zw, w23, acc[i]);
            }
        }
        float bias = enc_b2[t];
        #pragma unroll
        for (int i=0;i<N;i++) bufR[i*ST+t] = fmaxf(bias + acc[i].x + acc[i].y, 0.f);
    }
    __syncthreads();

    // ---- latent = h2 @ W3 + b3 (lanes 0..35) ----
    if (t < N*3) {
        int i = t / 3, c = t - i*3;
        float acc = enc_b3[c];
        for (int k=0;k<HID;k+=4) {
            v4f xv = *reinterpret_cast<const v4f*>(&bufR[i*ST+k]);
            acc = fmaf(xv.x, enc_w3[(k+0)*3+c], acc);
            acc = fmaf(xv.y, enc_w3[(k+1)*3+c], acc);
            acc = fmaf(xv.z, enc_w3[(k+2)*3+c], acc);
            acc = fmaf(xv.w, enc_w3[(k+3)*3+c], acc);
        }
        lat_s[t] = acc;
        out[OUT4 + (size_t)b*(N*3) + t] = acc;
        if (c == 2) x0_s[i] = acc;
    }
    __syncthreads();

    // ---- skip connection -> registers (lane-private by channel t) ----
    float skipv[N];
    {
        float w0 = skip_w[t], w1 = skip_w[HID+t], w2 = skip_w[2*HID+t];
        float bias = skip_b[t];
        #pragma unroll
        for (int i=0;i<N;i++) {
            float v = bias;
            v = fmaf(lat_s[i*3+0], w0, v);
            v = fmaf(lat_s[i*3+1], w1, v);
            v = fmaf(lat_s[i*3+2], w2, v);
            skipv[i] = v;
        }
    }

    // ---- Gabriel adjacency -> byte matrix, then row bitmasks ----
    for (int p = t; p < N*N; p += 64) {
        int i = p / N, j = p - i*N;
        int g = 0;
        if (i != j) {
            float pix = lat_s[i*3], piy = lat_s[i*3+1];
            float pjx = lat_s[j*3], pjy = lat_s[j*3+1];
            float mx = (pix + pjx) * 0.5f, my = (piy + pjy) * 0.5f;
            float dx = pix - pjx, dy = piy - pjy;
            float r2 = (dx*dx + dy*dy) * 0.25f;
            g = 1;
            #pragma unroll
            for (int k=0;k<N;k++) {
                if (k == i || k == j) continue;
                float ex = lat_s[k*3] - mx, ey = lat_s[k*3+1] - my;
                float d2 = ex*ex + ey*ey;
                g &= (d2 > r2) ? 1 : 0;
            }
        }
        gab8[p] = (unsigned char)g;
    }
    __syncthreads();
    if (t < N) {
        unsigned m = 1u << t;   // diagonal
        #pragma unroll
        for (int j=0;j<N;j++)
            if (gab8[t*N+j] | gab8[j*N+t]) m |= 1u << j;
        adjm_s[t] = m;
    }

    // ---- GATv2 core ----
    auto gat_core = [&](const float* __restrict__ gb, float* __restrict__ xout,
                        bool useSkip) {
        __syncthreads();   // xl/xr/att_s staged; also covers adjm_s on first call
        {
            // pairs: p0=t, p1=t+64, p2=t+128 (valid for t<16; clamp others, skip store)
            const int p0 = t, p1 = t + 64;
            const int p2c = (t < 16) ? (t + 128) : 143;
            const int i0 = p0 / N, j0 = p0 - i0*N;
            const int i1 = p1 / N, j1 = p1 - i1*N;
            const int i2 = p2c / N, j2 = p2c - i2*N;
            v2f a0 = z2, a1 = z2, a2 = z2;
            for (int h=0; h<HID; h+=4) {
                v4f at4 = *reinterpret_cast<const v4f*>(&att_s[h]);
                {
                    v4f xl4 = *reinterpret_cast<const v4f*>(&bufL[j0*ST+h]);
                    v4f xr4 = *reinterpret_cast<const v4f*>(&bufR[i0*ST+h]);
                    v2f s = xl4.xy + xr4.xy;
                    v2f l = __builtin_elementwise_fma(slope2, __builtin_elementwise_min(s, z2),
                                                     __builtin_elementwise_max(s, z2));
                    a0 = __builtin_elementwise_fma(at4.xy, l, a0);
                    s = xl4.zw + xr4.zw;
                    l = __builtin_elementwise_fma(slope2, __builtin_elementwise_min(s, z2),
                                                  __builtin_elementwise_max(s, z2));
                    a0 = __builtin_elementwise_fma(at4.zw, l, a0);
                }
                {
                    v4f xl4 = *reinterpret_cast<const v4f*>(&bufL[j1*ST+h]);
                    v4f xr4 = *reinterpret_cast<const v4f*>(&bufR[i1*ST+h]);
                    v2f s = xl4.xy + xr4.xy;
                    v2f l = __builtin_elementwise_fma(slope2, __builtin_elementwise_min(s, z2),
                                                     __builtin_elementwise_max(s, z2));
                    a1 = __builtin_elementwise_fma(at4.xy, l, a1);
                    s = xl4.zw + xr4.zw;
                    l = __builtin_elementwise_fma(slope2, __builtin_elementwise_min(s, z2),
                                                  __builtin_elementwise_max(s, z2));
                    a1 = __builtin_elementwise_fma(at4.zw, l, a1);
                }
                {
                    v4f xl4 = *reinterpret_cast<const v4f*>(&bufL[j2*ST+h]);
                    v4f xr4 = *reinterpret_cast<const v4f*>(&bufR[i2*ST+h]);
                    v2f s = xl4.xy + xr4.xy;
                    v2f l = __builtin_elementwise_fma(slope2, __builtin_elementwise_min(s, z2),
                                                     __builtin_elementwise_max(s, z2));
                    a2 = __builtin_elementwise_fma(at4.xy, l, a2);
                    s = xl4.zw + xr4.zw;
                    l = __builtin_elementwise_fma(slope2, __builtin_elementwise_min(s, z2),
                                                  __builtin_elementwise_max(s, z2));
                    a2 = __builtin_elementwise_fma(at4.zw, l, a2);
                }
            }
            float e0 = a0.x + a0.y, e1 = a1.x + a1.y, e2 = a2.x + a2.y;
            e_s[p0] = ((adjm_s[i0] >> j0) & 1u) ? e0 : -1e9f;
            e_s[p1] = ((adjm_s[i1] >> j1) & 1u) ? e1 : -1e9f;
            if (t < 16) e_s[p2c] = ((adjm_s[i2] >> j2) & 1u) ? e2 : -1e9f;
        }
        __syncthreads();
        if (t < N) {   // row softmax
            float m = -2e9f;
            #pragma unroll
            for (int j=0;j<N;j++) m = fmaxf(m, e_s[t*N+j]);
            float tmp[N]; float sum = 0.f;
            #pragma unroll
            for (int j=0;j<N;j++) { float v = __expf(e_s[t*N+j] - m); tmp[j] = v; sum += v; }
            float inv = 1.0f / sum;
            #pragma unroll
            for (int j=0;j<N;j++) e_s[t*N+j] = tmp[j] * inv;
        }
        __syncthreads();
        {
            float bias = gb[t];
            #pragma unroll
            for (int i=0;i<N;i++) {
                v2f acc2 = z2;
                #pragma unroll
                for (int j=0;j<N;j+=2) {
                    v2f e2 = *reinterpret_cast<const v2f*>(&e_s[i*N+j]);
                    v2f x2 = {bufL[j*ST+t], bufL[(j+1)*ST+t]};
                    acc2 = __builtin_elementwise_fma(e2, x2, acc2);
                }
                float r = bias + acc2.x + acc2.y;
                if (useSkip) r = fmaf(ALPHA, skipv[i], r);
                xout[i*ST+t] = fmaxf(r, 0.f);
            }
        }
        __syncthreads();
    };

    // ---- stage xl/xr (packed fp32; transposed weights if TW) ----
    auto stage_lr = [&](const float* __restrict__ xin,
                        const float* __restrict__ wl, const float* __restrict__ wr,
                        const float* __restrict__ wlT, const float* __restrict__ wrT,
                        const float* __restrict__ att) {
        att_s[t] = att[t];
        v2f al[N], ar[N];
        #pragma unroll
        for (int i=0;i<N;i++) { al[i] = z2; ar[i] = z2; }
        for (int c=0;c<HID;c+=4) {
            v2f wl01, wl23, wr01, wr23;
            if (TW) {
                v4f wl4 = *reinterpret_cast<const v4f*>(&wlT[c]);
                v4f wr4 = *reinterpret_cast<const v4f*>(&wrT[c]);
                wl01 = wl4.xy; wl23 = wl4.zw;
                wr01 = wr4.xy; wr23 = wr4.zw;
            } else {
                wl01 = (v2f){wl[(c+0)*HID+t], wl[(c+1)*HID+t]};
                wl23 = (v2f){wl[(c+2)*HID+t], wl[(c+3)*HID+t]};
                wr01 = (v2f){wr[(c+0)*HID+t], wr[(c+1)*HID+t]};
                wr23 = (v2f){wr[(c+2)*HID+t], wr[(c+3)*HID+t]};
            }
            #pragma unroll
            for (int i=0;i<N;i++) {
                v4f xv = *reinterpret_cast<const v4f*>(&xin[i*ST+c]);
                al[i] = __builtin_elementwise_fma(xv.xy, wl01, al[i]);
                al[i] = __builtin_elementwise_fma(xv.zw, wl23, al[i]);
                ar[i] = __builtin_elementwise_fma(xv.xy, wr01, ar[i]);
                ar[i] = __builtin_elementwise_fma(xv.zw, wr23, ar[i]);
            }
        }
        #pragma unroll
        for (int i=0;i<N;i++) {
            bufL[i*ST+t] = al[i].x + al[i].y;
            bufR[i*ST+t] = ar[i].x + ar[i].y;
        }
    };

    // ---- GAT layer 1 (cin = 1) ----
    {
        att_s[t] = g1_att[t];
        float wlv = g1_wl[t], wrv = g1_wr[t];
        #pragma unroll
        for (int i=0;i<N;i++) {
            bufL[i*ST+t] = x0_s[i] * wlv;
            bufR[i*ST+t] = x0_s[i] * wrv;
        }
    }
    gat_core(g1_b, xA, false);          // x1 -> xA

    // ---- GAT layer 2 ----
    stage_lr(xA, g2_wl, g2_wr, g2wlT, g2wrT, g2_att);
    gat_core(g2_b, xB, false);          // x2 -> xB

    // ---- GAT layer 3 ----
    stage_lr(xB, g3_wl, g3_wr, g3wlT, g3wrT, g3_att);
    gat_core(g3_b, xA, true);           // x3 -> xA

    // ---- logits head ----
    if (t < N*4) {
        int i = t >> 2, c = t & 3;
        float acc = lab_b[c];
        for (int h=0;h<HID;h+=4) {
            v4f xv = *reinterpret_cast<const v4f*>(&xA[i*ST+h]);
            acc = fmaf(xv.x, lab_w[(h+0)*4+c], acc);
            acc = fmaf(xv.y, lab_w[(h+1)*4+c], acc);
            acc = fmaf(xv.z, lab_w[(h+2)*4+c], acc);
            acc = fmaf(xv.w, lab_w[(h+3)*4+c], acc);
        }
        out[OUT2 + (size_t)b*(N*4) + t] = acc;
    }

    // ---- GAT layer 4 ----
    stage_lr(xB, g4_wl, g4_wr, g4wlT, g4wrT, g4_att);
    gat_core(g4_b, xA, true);           // x4 -> xA

    // ---- values head ----
    if (t < N) {
        float acc = val_b[0];
        for (int h=0;h<HID;h+=4) {
            v4f xv = *reinterpret_cast<const v4f*>(&xA[t*ST+h]);
            acc = fmaf(xv.x, val_w[h+0], acc);
            acc = fmaf(xv.y, val_w[h+1], acc);
            acc = fmaf(xv.z, val_w[h+2], acc);
            acc = fmaf(xv.w, val_w[h+3], acc);
        }
        out[OUT3 + (size_t)b*N + t] = acc;
    }
}

extern "C" void kernel_launch(void* const* d_in, const int* in_sizes, int n_in,
                              void* d_out, int out_size, void* d_ws, size_t ws_size,
                              hipStream_t stream) {
    (void)in_sizes; (void)n_in; (void)out_size;
    const bool useT = (ws_size >= 7*4096*sizeof(float));
    if (useT) {
        prep_kernel<<<dim3(7*64), dim3(64), 0, stream>>>(
            (const float*)d_in[3],
            (const float*)d_in[11], (const float*)d_in[12],
            (const float*)d_in[15], (const float*)d_in[16],
            (const float*)d_in[19], (const float*)d_in[20],
            (float*)d_ws);
        gae_kernel<true><<<dim3(4096), dim3(64), 0, stream>>>(
            (const float*)d_in[0],
            (const float*)d_in[1],  (const float*)d_in[2],
            (const float*)d_in[3],  (const float*)d_in[4],
            (const float*)d_in[5],  (const float*)d_in[6],
            (const float*)d_in[7],  (const float*)d_in[8],  (const float*)d_in[9],  (const float*)d_in[10],
            (const float*)d_in[11], (const float*)d_in[12], (const float*)d_in[13], (const float*)d_in[14],
            (const float*)d_in[15], (const float*)d_in[16], (const float*)d_in[17], (const float*)d_in[18],
            (const float*)d_in[19], (const float*)d_in[20], (const float*)d_in[21], (const float*)d_in[22],
            (const float*)d_in[23], (const float*)d_in[24],
            (const float*)d_in[25], (const float*)d_in[26],
            (const float*)d_in[27], (const float*)d_in[28],
            (const float*)d_ws,
            (float*)d_out);
    } else {
        gae_kernel<false><<<dim3(4096), dim3(64), 0, stream>>>(
            (const float*)d_in[0],
            (const float*)d_in[1],  (const float*)d_in[2],
            (const float*)d_in[3],  (const float*)d_in[4],
            (const float*)d_in[5],  (const float*)d_in[6],
            (const float*)d_in[7],  (const float*)d_in[8],  (const float*)d_in[9],  (const float*)d_in[10],
            (const float*)d_in[11], (const float*)d_in[12], (const float*)d_in[13], (const float*)d_in[14],
            (const float*)d_in[15], (const float*)d_in[16], (const float*)d_in[17], (const float*)d_in[18],
            (const float*)d_in[19], (const float*)d_in[20], (const float*)d_in[21], (const float*)d_in[22],
            (const float*)d_in[23], (const float*)d_in[24],
            (const float*)d_in[25], (const float*)d_in[26],
            (const float*)d_in[27], (const float*)d_in[28],
            nullptr,
            (float*)d_out);
    }
}